// Round 7
// baseline (4104.123 us; speedup 1.0000x reference)
//
#include <hip/hip_runtime.h>
#include <cstdint>

#define T_STEPS 1024
#define BATCH   32
#define DIM     1024
#define RANK    128
#define BD      (BATCH*DIM)            // 32768
#define TBD     ((size_t)T_STEPS*BD)   // 33554432

typedef _Float16 half2v __attribute__((ext_vector_type(2)));

__device__ __forceinline__ float dot2f(uint32_t a, uint32_t b, float acc) {
#if __has_builtin(__builtin_amdgcn_fdot2)
  return __builtin_amdgcn_fdot2(__builtin_bit_cast(half2v, a),
                                __builtin_bit_cast(half2v, b), acc, false);
#else
  half2v xx = __builtin_bit_cast(half2v, a);
  half2v yy = __builtin_bit_cast(half2v, b);
  return acc + (float)xx[0]*(float)yy[0] + (float)xx[1]*(float)yy[1];
#endif
}

__device__ __forceinline__ float dot2x4(uint4 w, uint4 h, float acc) {
  acc = dot2f(w.x, h.x, acc); acc = dot2f(w.y, h.y, acc);
  acc = dot2f(w.z, h.z, acc); acc = dot2f(w.w, h.w, acc);
  return acc;
}

__device__ __forceinline__ uint16_t f16b(float x) {
  _Float16 h = (_Float16)x;
  return __builtin_bit_cast(unsigned short, h);
}
__device__ __forceinline__ uint32_t pack2(float a, float b) {
  return (uint32_t)f16b(a) | ((uint32_t)f16b(b) << 16);
}
__device__ __forceinline__ float fast_tanh(float x) {
  float e = __expf(2.0f*x);
  return 1.0f - 2.0f/(e + 1.0f);
}
__device__ __forceinline__ float fast_silu(float zz) {
  return zz / (1.0f + __expf(-zz));
}

// quad_perm broadcast of lane K (0..3) within each quad — VALU pipe, no LDS.
template<int K>
__device__ __forceinline__ uint32_t qbcast(uint32_t v) {
  return (uint32_t)__builtin_amdgcn_mov_dpp((int)v, K*0x55, 0xf, 0xf, true);
}
template<int K>
__device__ __forceinline__ uint4 qbcast4(uint4 v) {
  uint4 r;
  r.x = qbcast<K>(v.x); r.y = qbcast<K>(v.y);
  r.z = qbcast<K>(v.z); r.w = qbcast<K>(v.w);
  return r;
}
// xor-1 / xor-2 neighbor fetch via DPP quad_perm (VALU, not DS pipe).
template<int CTRL>
__device__ __forceinline__ float dpp_xorf(float v) {
  int t = __builtin_amdgcn_mov_dpp(__builtin_bit_cast(int, v), CTRL, 0xf, 0xf, true);
  return __builtin_bit_cast(float, t);
}

// barrier that does NOT drain vmcnt (only LDS ordering needed between phases)
__device__ __forceinline__ void lds_barrier() {
  asm volatile("s_waitcnt lgkmcnt(0)" ::: "memory");
  __builtin_amdgcn_s_barrier();
  __builtin_amdgcn_sched_barrier(0);
}

// ---------------------------------------------------------------------------
// K0: pack weights to f16 pairs in ws (s folded into U), h0 -> h-slot 0.
// ws layout (uint32 words):
//   [0]      vhw  [128][512]  V_h f16 pairs (word = adjacent d-pair)
//   [65536]  uhw2 [1024][64]  U'_h INTERLEAVED column pairs:
//                             word k of row d = pack(U[d][k]*s[k], U[d][k+64]*s[k+64])
//   [131072] vxw  [128][512]
//   [196608] uxw  [1024][64]  (plain pair layout, used by inp_kernel)
// ---------------------------------------------------------------------------
__global__ void prep_kernel(const float* __restrict__ Uh, const float* __restrict__ Vh,
                            const float* __restrict__ sh, const float* __restrict__ Ux,
                            const float* __restrict__ Vx, const float* __restrict__ sx,
                            const float* __restrict__ h0, uint32_t* __restrict__ ws32,
                            float* __restrict__ hout) {
  int i = blockIdx.x*blockDim.x + threadIdx.x;
  int n = gridDim.x*blockDim.x;
  for (int p = i; p < 65536; p += n) {
    int r = p >> 9, dp = p & 511;
    ws32[p] = pack2(Vh[r*1024 + 2*dp], Vh[r*1024 + 2*dp + 1]);
  }
  for (int p = i; p < 65536; p += n) {
    int d = p >> 6, k = p & 63;
    ws32[65536 + p] = pack2(Uh[d*128 + k]      * sh[k],
                            Uh[d*128 + 64 + k] * sh[64 + k]);
  }
  for (int p = i; p < 65536; p += n) {
    int r = p >> 9, dp = p & 511;
    ws32[131072 + p] = pack2(Vx[r*1024 + 2*dp], Vx[r*1024 + 2*dp + 1]);
  }
  for (int p = i; p < 65536; p += n) {
    int d = p >> 6, rp = p & 63;
    ws32[196608 + p] = pack2(Ux[d*128 + 2*rp]   * sx[2*rp],
                             Ux[d*128 + 2*rp+1] * sx[2*rp+1]);
  }
  for (int p = i; p < BD; p += n) hout[p] = h0[p];
}

// ---------------------------------------------------------------------------
// K1: input branch. One WG per timestep t. (unchanged)
// ---------------------------------------------------------------------------
__global__ __launch_bounds__(512, 4) void inp_kernel(
    const float* __restrict__ x, const uint32_t* __restrict__ ws32,
    const float* __restrict__ bias, float* __restrict__ hout) {
  const int t = blockIdx.x;
  const int l = threadIdx.x;  // 0..511
  __shared__ __attribute__((aligned(16))) uint32_t xs[32*516];
  __shared__ __attribute__((aligned(16))) uint16_t svx[BATCH*RANK];

  const float4* xg = (const float4*)(x + (size_t)t*BD);
  #pragma unroll
  for (int k = 0; k < 16; k++) {
    int i = l + 512*k;
    float4 v = xg[i];
    int bb = i >> 8;
    int d4 = i & 255;
    xs[bb*516 + d4*2]     = pack2(v.x, v.y);
    xs[bb*516 + d4*2 + 1] = pack2(v.z, v.w);
  }
  __syncthreads();

  const int q4 = l & 3;
  const int r  = l >> 2;
  const uint4* wrow = (const uint4*)(ws32 + 131072 + r*512);
  float acc0[8], acc1[8];
  #pragma unroll
  for (int bi = 0; bi < 8; bi++) { acc0[bi] = 0.f; acc1[bi] = 0.f; }
  #pragma unroll 4
  for (int J = 0; J < 128; J += 2) {
    uint4 w0 = wrow[J];
    uint4 w1 = wrow[J+1];
    #pragma unroll
    for (int bi = 0; bi < 8; bi++) {
      const uint4* xrow = (const uint4*)(xs + (4*bi + q4)*516);
      uint4 h0v = xrow[J];
      acc0[bi] = dot2f(w0.x, h0v.x, acc0[bi]);
      acc0[bi] = dot2f(w0.y, h0v.y, acc0[bi]);
      acc0[bi] = dot2f(w0.z, h0v.z, acc0[bi]);
      acc0[bi] = dot2f(w0.w, h0v.w, acc0[bi]);
      uint4 h1v = xrow[J+1];
      acc1[bi] = dot2f(w1.x, h1v.x, acc1[bi]);
      acc1[bi] = dot2f(w1.y, h1v.y, acc1[bi]);
      acc1[bi] = dot2f(w1.z, h1v.z, acc1[bi]);
      acc1[bi] = dot2f(w1.w, h1v.w, acc1[bi]);
    }
  }
  #pragma unroll
  for (int bi = 0; bi < 8; bi++)
    svx[(4*bi + q4)*RANK + r] = f16b(acc0[bi] + acc1[bi]);
  __syncthreads();

  const uint4* svx4 = (const uint4*)svx;
  float accb[BATCH];
  #pragma unroll 1
  for (int dd = 0; dd < 2; dd++) {
    int d = l + dd*512;
    const uint4* urow = (const uint4*)(ws32 + 196608 + d*64);
    #pragma unroll
    for (int bi = 0; bi < BATCH; bi++) accb[bi] = 0.f;
    #pragma unroll
    for (int RP = 0; RP < 16; RP++) {
      uint4 w = urow[RP];
      #pragma unroll
      for (int bi = 0; bi < BATCH; bi++) {
        uint4 sv = svx4[bi*16 + RP];
        accb[bi] = dot2f(w.x, sv.x, accb[bi]);
        accb[bi] = dot2f(w.y, sv.y, accb[bi]);
        accb[bi] = dot2f(w.z, sv.z, accb[bi]);
        accb[bi] = dot2f(w.w, sv.w, accb[bi]);
      }
    }
    float bv = bias[d];
    float* cslot = hout + (size_t)(t+1)*BD + d;
    #pragma unroll
    for (int bi = 0; bi < BATCH; bi++)
      cslot[(size_t)bi*DIM] = accb[bi] + bv;
  }
}

// ---------------------------------------------------------------------------
// K2: recurrence v7. One WG of 1024 threads (16 waves, 4/SIMD) per batch b.
// At 4 waves/EU the compiler MUST fit 128 VGPR (no heuristic fight), and
// 1024 lanes x 100 weight words = 400KB reg-resident + 112KB LDS = FULL
// weight residency (v4-v6 streamed 200-384KB/step from L2 = the bottleneck).
//  - Phase A: lane (w=l&31, rg=l>>5): V rows 4rg..4rg+3 x window w
//    (16 words) = 64 V regs (ALL of V in regs). h via 8 ds_read_b64 from
//    stagger-laid hbuf: window w at word 16w+2(w>>1) -> bank starts
//    injective up to 2x dup -> conflict-free. Reduce: DPP xor1/2 +
//    shfl xor4/8/16 within 32-lane groups; lanes w<4 write svh.
//  - Phase B: lane = row d=l; U 64 words: uq[9] regs (36) + 7 lane-major
//    LDS uint4 (gold b128), loaded per-quarter (caps reg pressure).
//    svh via quad-read + DPP broadcast.
// ---------------------------------------------------------------------------
__global__ __launch_bounds__(1024) void rec_kernel(
    const uint32_t* __restrict__ ws32, const float* __restrict__ z,
    float* __restrict__ outb) {
  const int b  = blockIdx.x;
  const int l  = threadIdx.x;   // 0..1023
  const int w  = l & 31;        // d-window (32 words of h-pairs per... 16 words)
  const int rg = l >> 5;        // row-group 0..31
  const int m  = l & 3;
  float* hout = outb + TBD;
  const uint4* vhw4 = (const uint4*)ws32;            // V: row stride 128 uint4
  const uint4* uhw4 = (const uint4*)(ws32 + 65536);  // U: row stride 16 uint4

  __shared__ __attribute__((aligned(16))) uint4    ulds[7*1024];  // 112 KB
  __shared__ __attribute__((aligned(16))) uint32_t hbuf[544];     // staggered h
  __shared__ __attribute__((aligned(16))) uint32_t svh32[64];     // 256 B

  // V rows 4rg..4rg+3, window w -> regs (64 VGPRs) == entire V in the WG
  uint4 vw[4][4];
  #pragma unroll
  for (int r = 0; r < 4; r++) {
    #pragma unroll
    for (int c = 0; c < 4; c++) vw[r][c] = vhw4[(4*rg + r)*128 + w*4 + c];
  }
  // U row l: words 0..35 -> regs (36 VGPRs); words 36..63 -> ulds lane-major
  uint4 uq[9];
  #pragma unroll
  for (int J = 0; J < 9; J++) uq[J] = uhw4[l*16 + J];
  #pragma unroll
  for (int J = 0; J < 7; J++) ulds[J*1024 + l] = uhw4[l*16 + 9 + J];

  // init hbuf from h0: word j at 16*(j>>4) + 2*((j>>4)>>1) + (j&15)
  if (l < 512) {
    const float2 v = ((const float2*)(hout + (size_t)b*DIM))[l];
    int w0 = l >> 4;
    hbuf[16*w0 + 2*(w0 >> 1) + (l & 15)] = pack2(v.x, v.y);
  }
  __syncthreads();

  const float* zp = z + (size_t)b*DIM + l;
  float*       cp = hout + BD + (size_t)b*DIM + l;   // slot t+1: c -> h
  float*       op = outb + (size_t)b*DIM + l;
  const uint2* hb2  = (const uint2*)hbuf;
  const uint4* svh4 = (const uint4*)svh32;
  const int ho = 8*w + (w >> 1);        // uint2 index of window base
  // h-write index (phase B): lane d=l writes f16 h[d] into word (l>>1)
  const int hw_widx = 2*(16*rg + 2*(rg >> 1) + ((l >> 1) & 15)) + (l & 1);

  #pragma unroll 1
  for (int t = 0; t < T_STEPS; t++) {
    // prefetch c (slot t+1), z (slot t): consumed ~end of phase B
    float cc = *cp;
    float zz = *zp;

    // ---- phase A: 4 rows x 16-word window, V in regs, h via 8 b64 ----
    float a[4] = {0.f, 0.f, 0.f, 0.f};
    #pragma unroll
    for (int c = 0; c < 4; c++) {
      uint2 hA = hb2[ho + 2*c];
      uint2 hB = hb2[ho + 2*c + 1];
      #pragma unroll
      for (int r = 0; r < 4; r++) {
        a[r] = dot2f(vw[r][c].x, hA.x, a[r]);
        a[r] = dot2f(vw[r][c].y, hA.y, a[r]);
        a[r] = dot2f(vw[r][c].z, hB.x, a[r]);
        a[r] = dot2f(vw[r][c].w, hB.y, a[r]);
      }
    }
    // reduce-scatter over the 32 window-lanes (lane bits 0..4 == w bits)
    float b2v[2];
    {
      const bool s0 = (w & 1);
      #pragma unroll
      for (int i = 0; i < 2; i++) {
        float keep = s0 ? a[2*i+1] : a[2*i];
        float send = s0 ? a[2*i]   : a[2*i+1];
        b2v[i] = keep + dpp_xorf<0xB1>(send);   // quad_perm xor1
      }
    }
    float s;
    {
      const bool s1 = (w >> 1) & 1;
      float keep = s1 ? b2v[1] : b2v[0];
      float send = s1 ? b2v[0] : b2v[1];
      s = keep + dpp_xorf<0x4E>(send);          // quad_perm xor2
    }
    s += __shfl_xor(s, 4);
    s += __shfl_xor(s, 8);
    s += __shfl_xor(s, 16);
    if (w < 4) {
      int row = 4*rg + w;                        // 0..127
      int idx = ((row & 63) << 1) | (row >> 6);  // pack (g, g+64) into word g
      ((uint16_t*)svh32)[idx] = f16b(s);
    }
    lds_barrier();

    // ---- phase B: row d=l over packed svh; quarters via quad-read+DPP ----
    float p = 0.f;
    { // quarter 0: words 0..15 (regs)
      uint4 svm = svh4[m]; uint4 sv;
      sv = qbcast4<0>(svm); p = dot2x4(uq[0], sv, p);
      sv = qbcast4<1>(svm); p = dot2x4(uq[1], sv, p);
      sv = qbcast4<2>(svm); p = dot2x4(uq[2], sv, p);
      sv = qbcast4<3>(svm); p = dot2x4(uq[3], sv, p);
    }
    { // quarter 1: words 16..31 (regs)
      uint4 svm = svh4[4 + m]; uint4 sv;
      sv = qbcast4<0>(svm); p = dot2x4(uq[4], sv, p);
      sv = qbcast4<1>(svm); p = dot2x4(uq[5], sv, p);
      sv = qbcast4<2>(svm); p = dot2x4(uq[6], sv, p);
      sv = qbcast4<3>(svm); p = dot2x4(uq[7], sv, p);
    }
    { // quarter 2: words 32..47 (uq[8] + 3 LDS)
      uint4 u9  = ulds[l];
      uint4 u10 = ulds[1024 + l];
      uint4 u11 = ulds[2048 + l];
      uint4 svm = svh4[8 + m]; uint4 sv;
      sv = qbcast4<0>(svm); p = dot2x4(uq[8], sv, p);
      sv = qbcast4<1>(svm); p = dot2x4(u9,  sv, p);
      sv = qbcast4<2>(svm); p = dot2x4(u10, sv, p);
      sv = qbcast4<3>(svm); p = dot2x4(u11, sv, p);
    }
    { // quarter 3: words 48..63 (4 LDS)
      uint4 u12 = ulds[3072 + l];
      uint4 u13 = ulds[4096 + l];
      uint4 u14 = ulds[5120 + l];
      uint4 u15 = ulds[6144 + l];
      uint4 svm = svh4[12 + m]; uint4 sv;
      sv = qbcast4<0>(svm); p = dot2x4(u12, sv, p);
      sv = qbcast4<1>(svm); p = dot2x4(u13, sv, p);
      sv = qbcast4<2>(svm); p = dot2x4(u14, sv, p);
      sv = qbcast4<3>(svm); p = dot2x4(u15, sv, p);
    }

    float hv = fast_tanh(p + cc);
    *cp = hv;                                   // h[t+1] (f32 output)
    ((uint16_t*)hbuf)[hw_widx] = f16b(hv);      // h for next step (staggered)
    *op = hv * fast_silu(zz);                   // out[t]
    lds_barrier();

    cp += BD; zp += BD; op += BD;
  }
}

extern "C" void kernel_launch(void* const* d_in, const int* in_sizes, int n_in,
                              void* d_out, int out_size, void* d_ws, size_t ws_size,
                              hipStream_t stream) {
  const float* x  = (const float*)d_in[0];
  const float* z  = (const float*)d_in[1];
  const float* h0 = (const float*)d_in[2];
  const float* Uh = (const float*)d_in[3];
  const float* Vh = (const float*)d_in[4];
  const float* sh = (const float*)d_in[5];
  const float* Ux = (const float*)d_in[6];
  const float* Vx = (const float*)d_in[7];
  const float* sx = (const float*)d_in[8];
  const float* bb = (const float*)d_in[9];
  float* outb = (float*)d_out;
  uint32_t* ws32 = (uint32_t*)d_ws;   // needs 1 MiB

  prep_kernel<<<512, 256, 0, stream>>>(Uh, Vh, sh, Ux, Vx, sx, h0, ws32, outb + TBD);
  inp_kernel<<<T_STEPS, 512, 0, stream>>>(x, ws32, bb, outb + TBD);
  rec_kernel<<<BATCH, 1024, 0, stream>>>(ws32, z, outb);
}

// Round 8
// 3001.795 us; speedup vs baseline: 1.3672x; 1.3672x over previous
//
#include <hip/hip_runtime.h>
#include <cstdint>

#define T_STEPS 1024
#define BATCH   32
#define DIM     1024
#define RANK    128
#define BD      (BATCH*DIM)            // 32768
#define TBD     ((size_t)T_STEPS*BD)   // 33554432

typedef _Float16 half2v __attribute__((ext_vector_type(2)));

__device__ __forceinline__ float dot2f(uint32_t a, uint32_t b, float acc) {
#if __has_builtin(__builtin_amdgcn_fdot2)
  return __builtin_amdgcn_fdot2(__builtin_bit_cast(half2v, a),
                                __builtin_bit_cast(half2v, b), acc, false);
#else
  half2v xx = __builtin_bit_cast(half2v, a);
  half2v yy = __builtin_bit_cast(half2v, b);
  return acc + (float)xx[0]*(float)yy[0] + (float)xx[1]*(float)yy[1];
#endif
}

__device__ __forceinline__ float dot2x4(uint4 w, uint4 h, float acc) {
  acc = dot2f(w.x, h.x, acc); acc = dot2f(w.y, h.y, acc);
  acc = dot2f(w.z, h.z, acc); acc = dot2f(w.w, h.w, acc);
  return acc;
}

__device__ __forceinline__ uint16_t f16b(float x) {
  _Float16 h = (_Float16)x;
  return __builtin_bit_cast(unsigned short, h);
}
__device__ __forceinline__ uint32_t pack2(float a, float b) {
  return (uint32_t)f16b(a) | ((uint32_t)f16b(b) << 16);
}
__device__ __forceinline__ float fast_tanh(float x) {
  float e = __expf(2.0f*x);
  return 1.0f - 2.0f/(e + 1.0f);
}
__device__ __forceinline__ float fast_silu(float zz) {
  return zz / (1.0f + __expf(-zz));
}

// Opaque identity: makes the value's origin unknown to the compiler so the
// machine scheduler CANNOT rematerialize it by re-loading from global memory.
// This is the fix for R3-R7: the scheduler kept remat'ing weight loads to
// shrink pressure to the 128-reg occupancy bucket, silently streaming the
// "register-resident" weights from L2 every step.
__device__ __forceinline__ void pin4(uint4 &v) {
  asm volatile("" : "+v"(v.x), "+v"(v.y), "+v"(v.z), "+v"(v.w));
}

// quad_perm broadcast of lane K (0..3) within each quad — VALU pipe, no LDS.
template<int K>
__device__ __forceinline__ uint32_t qbcast(uint32_t v) {
  return (uint32_t)__builtin_amdgcn_mov_dpp((int)v, K*0x55, 0xf, 0xf, true);
}
template<int K>
__device__ __forceinline__ uint4 qbcast4(uint4 v) {
  uint4 r;
  r.x = qbcast<K>(v.x); r.y = qbcast<K>(v.y);
  r.z = qbcast<K>(v.z); r.w = qbcast<K>(v.w);
  return r;
}
// xor-1 / xor-2 neighbor fetch via DPP quad_perm (VALU, not DS pipe).
template<int CTRL>
__device__ __forceinline__ float dpp_xorf(float v) {
  int t = __builtin_amdgcn_mov_dpp(__builtin_bit_cast(int, v), CTRL, 0xf, 0xf, true);
  return __builtin_bit_cast(float, t);
}

// barrier that does NOT drain vmcnt (only LDS ordering needed between phases)
__device__ __forceinline__ void lds_barrier() {
  asm volatile("s_waitcnt lgkmcnt(0)" ::: "memory");
  __builtin_amdgcn_s_barrier();
  __builtin_amdgcn_sched_barrier(0);
}

// ---------------------------------------------------------------------------
// K0: pack weights to f16 pairs in ws (s folded into U), h0 -> h-slot 0.
// ws layout (uint32 words):
//   [0]      vhw  [128][512]  V_h f16 pairs (word = adjacent d-pair)
//   [65536]  uhw2 [1024][64]  U'_h INTERLEAVED column pairs:
//                             word k of row d = pack(U[d][k]*s[k], U[d][k+64]*s[k+64])
//   [131072] vxw  [128][512]
//   [196608] uxw  [1024][64]  (plain pair layout, used by inp_kernel)
// ---------------------------------------------------------------------------
__global__ void prep_kernel(const float* __restrict__ Uh, const float* __restrict__ Vh,
                            const float* __restrict__ sh, const float* __restrict__ Ux,
                            const float* __restrict__ Vx, const float* __restrict__ sx,
                            const float* __restrict__ h0, uint32_t* __restrict__ ws32,
                            float* __restrict__ hout) {
  int i = blockIdx.x*blockDim.x + threadIdx.x;
  int n = gridDim.x*blockDim.x;
  for (int p = i; p < 65536; p += n) {
    int r = p >> 9, dp = p & 511;
    ws32[p] = pack2(Vh[r*1024 + 2*dp], Vh[r*1024 + 2*dp + 1]);
  }
  for (int p = i; p < 65536; p += n) {
    int d = p >> 6, k = p & 63;
    ws32[65536 + p] = pack2(Uh[d*128 + k]      * sh[k],
                            Uh[d*128 + 64 + k] * sh[64 + k]);
  }
  for (int p = i; p < 65536; p += n) {
    int r = p >> 9, dp = p & 511;
    ws32[131072 + p] = pack2(Vx[r*1024 + 2*dp], Vx[r*1024 + 2*dp + 1]);
  }
  for (int p = i; p < 65536; p += n) {
    int d = p >> 6, rp = p & 63;
    ws32[196608 + p] = pack2(Ux[d*128 + 2*rp]   * sx[2*rp],
                             Ux[d*128 + 2*rp+1] * sx[2*rp+1]);
  }
  for (int p = i; p < BD; p += n) hout[p] = h0[p];
}

// ---------------------------------------------------------------------------
// K1: input branch. One WG per timestep t. (unchanged)
// ---------------------------------------------------------------------------
__global__ __launch_bounds__(512, 4) void inp_kernel(
    const float* __restrict__ x, const uint32_t* __restrict__ ws32,
    const float* __restrict__ bias, float* __restrict__ hout) {
  const int t = blockIdx.x;
  const int l = threadIdx.x;  // 0..511
  __shared__ __attribute__((aligned(16))) uint32_t xs[32*516];
  __shared__ __attribute__((aligned(16))) uint16_t svx[BATCH*RANK];

  const float4* xg = (const float4*)(x + (size_t)t*BD);
  #pragma unroll
  for (int k = 0; k < 16; k++) {
    int i = l + 512*k;
    float4 v = xg[i];
    int bb = i >> 8;
    int d4 = i & 255;
    xs[bb*516 + d4*2]     = pack2(v.x, v.y);
    xs[bb*516 + d4*2 + 1] = pack2(v.z, v.w);
  }
  __syncthreads();

  const int q4 = l & 3;
  const int r  = l >> 2;
  const uint4* wrow = (const uint4*)(ws32 + 131072 + r*512);
  float acc0[8], acc1[8];
  #pragma unroll
  for (int bi = 0; bi < 8; bi++) { acc0[bi] = 0.f; acc1[bi] = 0.f; }
  #pragma unroll 4
  for (int J = 0; J < 128; J += 2) {
    uint4 w0 = wrow[J];
    uint4 w1 = wrow[J+1];
    #pragma unroll
    for (int bi = 0; bi < 8; bi++) {
      const uint4* xrow = (const uint4*)(xs + (4*bi + q4)*516);
      uint4 h0v = xrow[J];
      acc0[bi] = dot2f(w0.x, h0v.x, acc0[bi]);
      acc0[bi] = dot2f(w0.y, h0v.y, acc0[bi]);
      acc0[bi] = dot2f(w0.z, h0v.z, acc0[bi]);
      acc0[bi] = dot2f(w0.w, h0v.w, acc0[bi]);
      uint4 h1v = xrow[J+1];
      acc1[bi] = dot2f(w1.x, h1v.x, acc1[bi]);
      acc1[bi] = dot2f(w1.y, h1v.y, acc1[bi]);
      acc1[bi] = dot2f(w1.z, h1v.z, acc1[bi]);
      acc1[bi] = dot2f(w1.w, h1v.w, acc1[bi]);
    }
  }
  #pragma unroll
  for (int bi = 0; bi < 8; bi++)
    svx[(4*bi + q4)*RANK + r] = f16b(acc0[bi] + acc1[bi]);
  __syncthreads();

  const uint4* svx4 = (const uint4*)svx;
  float accb[BATCH];
  #pragma unroll 1
  for (int dd = 0; dd < 2; dd++) {
    int d = l + dd*512;
    const uint4* urow = (const uint4*)(ws32 + 196608 + d*64);
    #pragma unroll
    for (int bi = 0; bi < BATCH; bi++) accb[bi] = 0.f;
    #pragma unroll
    for (int RP = 0; RP < 16; RP++) {
      uint4 w = urow[RP];
      #pragma unroll
      for (int bi = 0; bi < BATCH; bi++) {
        uint4 sv = svx4[bi*16 + RP];
        accb[bi] = dot2f(w.x, sv.x, accb[bi]);
        accb[bi] = dot2f(w.y, sv.y, accb[bi]);
        accb[bi] = dot2f(w.z, sv.z, accb[bi]);
        accb[bi] = dot2f(w.w, sv.w, accb[bi]);
      }
    }
    float bv = bias[d];
    float* cslot = hout + (size_t)(t+1)*BD + d;
    #pragma unroll
    for (int bi = 0; bi < BATCH; bi++)
      cslot[(size_t)bi*DIM] = accb[bi] + bv;
  }
}

// ---------------------------------------------------------------------------
// K2: recurrence v8 = v6 structure + pin4() on all weight registers.
// One WG (512 thr = 8 waves, 2 waves/SIMD) per batch b.
// Weight residency (512 KB total):
//   regs 384 KB: V rows 8R8+0..5 (96 VGPR) + U words 0..47 of rows 2l,2l+1 (96)
//     -> PINNED via opaque asm so the scheduler cannot remat them from L2.
//   LDS  128 KB: V rows 8R8+6,7 (64 KB, interleave) + U words 48..63 (64 KB)
// waves_per_eu(2,2) keeps the RA budget at 256 regs/lane.
// ---------------------------------------------------------------------------
__global__ __launch_bounds__(512) __attribute__((amdgpu_waves_per_eu(2, 2)))
void rec_kernel(
    const uint32_t* __restrict__ ws32, const float* __restrict__ z,
    float* __restrict__ outb) {
  const int b  = blockIdx.x;
  const int l  = threadIdx.x;  // 0..511
  const int W  = l & 31;
  const int R8 = l >> 5;       // 0..15
  const int m  = l & 3;
  float* hout = outb + TBD;
  const uint4* vhw4 = (const uint4*)ws32;            // V: row stride 128 uint4
  const uint4* uhw4 = (const uint4*)(ws32 + 65536);  // U: row stride 16 uint4

  __shared__ __attribute__((aligned(16))) uint4    vlds[4096];   // 64 KB
  __shared__ __attribute__((aligned(16))) uint4    ulds[4096];   // 64 KB
  __shared__ __attribute__((aligned(16))) uint4    hbuf[32*5];   // 2.5 KB staggered
  __shared__ __attribute__((aligned(16))) uint32_t svh32[64];    // 256 B

  // V rows 8R8+0..5, window [16W,16W+16) pairs -> regs (96 VGPRs), pinned
  uint4 vw[6][4];
  #pragma unroll
  for (int r = 0; r < 6; r++) {
    #pragma unroll
    for (int c = 0; c < 4; c++) vw[r][c] = vhw4[(8*R8 + r)*128 + W*4 + c];
  }
  #pragma unroll
  for (int r = 0; r < 6; r++) {
    #pragma unroll
    for (int c = 0; c < 4; c++) pin4(vw[r][c]);
  }
  // V rows 8R8+6,7 -> vlds (interleaved: idx = R8*256 + rr*128 + c*32 + W)
  #pragma unroll
  for (int rr = 0; rr < 2; rr++) {
    #pragma unroll
    for (int c = 0; c < 4; c++)
      vlds[R8*256 + rr*128 + c*32 + W] = vhw4[(8*R8 + 6 + rr)*128 + W*4 + c];
  }
  // U rows 2l,2l+1 words 0..47 -> regs (96 VGPRs), pinned
  uint4 uqr0[12], uqr1[12];
  #pragma unroll
  for (int J = 0; J < 12; J++) { uqr0[J] = uhw4[(2*l)*16 + J]; uqr1[J] = uhw4[(2*l+1)*16 + J]; }
  #pragma unroll
  for (int J = 0; J < 12; J++) { pin4(uqr0[J]); pin4(uqr1[J]); }
  // U words 48..63 -> ulds (lane-major: ulds[J*512 + l], J<4: row 2l, J>=4: row 2l+1)
  #pragma unroll
  for (int J = 0; J < 8; J++)
    ulds[J*512 + l] = uhw4[(2*l + (J >> 2))*16 + 12 + (J & 3)];
  // init hbuf from h0 (pair p=l at word 20*(p>>4) + (p&15))
  {
    const float2 v = ((const float2*)(hout + (size_t)b*DIM))[l];
    ((uint32_t*)hbuf)[20*(l>>4) + (l&15)] = pack2(v.x, v.y);
  }
  __syncthreads();

  const float2* zp2 = (const float2*)(z + (size_t)b*DIM) + l;
  float2*       cp2 = (float2*)(hout + BD + (size_t)b*DIM) + l;
  float2*       op2 = (float2*)(outb + (size_t)b*DIM) + l;
  const uint4*  hb4  = hbuf + W*5;
  const uint4*  svh4 = (const uint4*)svh32;
  const int vbase = R8*256;

  #pragma unroll 1
  for (int t = 0; t < T_STEPS; t++) {
    // ---- issue c (slot t+1) and z (slot t) loads: consumed in phase B ----
    float2 cc = *cp2;
    float2 zz = *zp2;

    // ---- phase A: 8 rows (6 reg + 2 LDS, per-c pipelined) x 16-pair window ----
    float a[8] = {0.f,0.f,0.f,0.f,0.f,0.f,0.f,0.f};
    uint4 vAc = vlds[vbase + W];
    uint4 vBc = vlds[vbase + 128 + W];
    uint4 hvc = hb4[0];
    #pragma unroll
    for (int c = 0; c < 4; c++) {
      uint4 vAn, vBn, hvn;
      if (c < 3) {
        vAn = vlds[vbase + (c+1)*32 + W];
        vBn = vlds[vbase + 128 + (c+1)*32 + W];
        hvn = hb4[c+1];
      }
      a[0] = dot2x4(vw[0][c], hvc, a[0]);
      a[1] = dot2x4(vw[1][c], hvc, a[1]);
      a[2] = dot2x4(vw[2][c], hvc, a[2]);
      a[3] = dot2x4(vw[3][c], hvc, a[3]);
      a[4] = dot2x4(vw[4][c], hvc, a[4]);
      a[5] = dot2x4(vw[5][c], hvc, a[5]);
      a[6] = dot2x4(vAc, hvc, a[6]);
      a[7] = dot2x4(vBc, hvc, a[7]);
      if (c < 3) { vAc = vAn; vBc = vBn; hvc = hvn; }
    }
    // reduce-scatter: row 8R8+(W&7) total lands in every lane of its group
    float b4[4];
    {
      const bool s0 = (W & 1);
      #pragma unroll
      for (int i = 0; i < 4; i++) {
        float keep = s0 ? a[2*i+1] : a[2*i];
        float send = s0 ? a[2*i]   : a[2*i+1];
        b4[i] = keep + dpp_xorf<0xB1>(send);   // quad_perm(1,0,3,2) = xor1
      }
    }
    float c2[2];
    {
      const bool s1 = (W >> 1) & 1;
      #pragma unroll
      for (int i = 0; i < 2; i++) {
        float keep = s1 ? b4[2*i+1] : b4[2*i];
        float send = s1 ? b4[2*i]   : b4[2*i+1];
        c2[i] = keep + dpp_xorf<0x4E>(send);   // quad_perm(2,3,0,1) = xor2
      }
    }
    float s;
    {
      const bool s2 = (W >> 2) & 1;
      float keep = s2 ? c2[1] : c2[0];
      float send = s2 ? c2[0] : c2[1];
      s = keep + __shfl_xor(send, 4);
    }
    s += __shfl_xor(s, 8);
    s += __shfl_xor(s, 16);
    if (W < 8) {
      int row = 8*R8 + W;                         // 0..127
      int idx = ((row & 63) << 1) | (row >> 6);   // packed (g, g+64) halves
      ((uint16_t*)svh32)[idx] = f16b(s);
    }
    lds_barrier();

    // ---- phase B: rows d=2l,2l+1; svh quad-read + DPP broadcast ----
    float p0 = 0.f, p1 = 0.f;
    { // quarter 0: k4 0..3 (regs)
      uint4 svm = svh4[m];
      uint4 sv;
      sv = qbcast4<0>(svm); p0 = dot2x4(uqr0[0], sv, p0); p1 = dot2x4(uqr1[0], sv, p1);
      sv = qbcast4<1>(svm); p0 = dot2x4(uqr0[1], sv, p0); p1 = dot2x4(uqr1[1], sv, p1);
      sv = qbcast4<2>(svm); p0 = dot2x4(uqr0[2], sv, p0); p1 = dot2x4(uqr1[2], sv, p1);
      sv = qbcast4<3>(svm); p0 = dot2x4(uqr0[3], sv, p0); p1 = dot2x4(uqr1[3], sv, p1);
    }
    uint4 uL0[4];
    #pragma unroll
    for (int i = 0; i < 4; i++) uL0[i] = ulds[i*512 + l];
    { // quarter 1: k4 4..7 (regs)
      uint4 svm = svh4[4 + m];
      uint4 sv;
      sv = qbcast4<0>(svm); p0 = dot2x4(uqr0[4], sv, p0); p1 = dot2x4(uqr1[4], sv, p1);
      sv = qbcast4<1>(svm); p0 = dot2x4(uqr0[5], sv, p0); p1 = dot2x4(uqr1[5], sv, p1);
      sv = qbcast4<2>(svm); p0 = dot2x4(uqr0[6], sv, p0); p1 = dot2x4(uqr1[6], sv, p1);
      sv = qbcast4<3>(svm); p0 = dot2x4(uqr0[7], sv, p0); p1 = dot2x4(uqr1[7], sv, p1);
    }
    uint4 uL1[4];
    #pragma unroll
    for (int i = 0; i < 4; i++) uL1[i] = ulds[(4+i)*512 + l];
    { // quarter 2: k4 8..11 (regs)
      uint4 svm = svh4[8 + m];
      uint4 sv;
      sv = qbcast4<0>(svm); p0 = dot2x4(uqr0[8],  sv, p0); p1 = dot2x4(uqr1[8],  sv, p1);
      sv = qbcast4<1>(svm); p0 = dot2x4(uqr0[9],  sv, p0); p1 = dot2x4(uqr1[9],  sv, p1);
      sv = qbcast4<2>(svm); p0 = dot2x4(uqr0[10], sv, p0); p1 = dot2x4(uqr1[10], sv, p1);
      sv = qbcast4<3>(svm); p0 = dot2x4(uqr0[11], sv, p0); p1 = dot2x4(uqr1[11], sv, p1);
    }
    { // quarter 3: k4 12..15 (LDS)
      uint4 svm = svh4[12 + m];
      uint4 sv;
      sv = qbcast4<0>(svm); p0 = dot2x4(uL0[0], sv, p0); p1 = dot2x4(uL1[0], sv, p1);
      sv = qbcast4<1>(svm); p0 = dot2x4(uL0[1], sv, p0); p1 = dot2x4(uL1[1], sv, p1);
      sv = qbcast4<2>(svm); p0 = dot2x4(uL0[2], sv, p0); p1 = dot2x4(uL1[2], sv, p1);
      sv = qbcast4<3>(svm); p0 = dot2x4(uL0[3], sv, p0); p1 = dot2x4(uL1[3], sv, p1);
    }

    float hv0 = fast_tanh(p0 + cc.x);
    float hv1 = fast_tanh(p1 + cc.y);
    *cp2 = make_float2(hv0, hv1);                             // h[t+1] (f32 out)
    ((uint32_t*)hbuf)[20*(l>>4) + (l&15)] = pack2(hv0, hv1);  // h for next step
    *op2 = make_float2(hv0 * fast_silu(zz.x), hv1 * fast_silu(zz.y));
    lds_barrier();

    cp2 += BD/2; zp2 += BD/2; op2 += BD/2;
  }
}

extern "C" void kernel_launch(void* const* d_in, const int* in_sizes, int n_in,
                              void* d_out, int out_size, void* d_ws, size_t ws_size,
                              hipStream_t stream) {
  const float* x  = (const float*)d_in[0];
  const float* z  = (const float*)d_in[1];
  const float* h0 = (const float*)d_in[2];
  const float* Uh = (const float*)d_in[3];
  const float* Vh = (const float*)d_in[4];
  const float* sh = (const float*)d_in[5];
  const float* Ux = (const float*)d_in[6];
  const float* Vx = (const float*)d_in[7];
  const float* sx = (const float*)d_in[8];
  const float* bb = (const float*)d_in[9];
  float* outb = (float*)d_out;
  uint32_t* ws32 = (uint32_t*)d_ws;   // needs 1 MiB

  prep_kernel<<<512, 256, 0, stream>>>(Uh, Vh, sh, Ux, Vx, sx, h0, ws32, outb + TBD);
  inp_kernel<<<T_STEPS, 512, 0, stream>>>(x, ws32, bb, outb + TBD);
  rec_kernel<<<BATCH, 512, 0, stream>>>(ws32, z, outb);
}

// Round 9
// 2441.408 us; speedup vs baseline: 1.6810x; 1.2295x over previous
//
#include <hip/hip_runtime.h>
#include <cstdint>

#define T_STEPS 1024
#define BATCH   32
#define DIM     1024
#define RANK    128
#define BD      (BATCH*DIM)            // 32768
#define TBD     ((size_t)T_STEPS*BD)   // 33554432

typedef _Float16 half2v __attribute__((ext_vector_type(2)));

__device__ __forceinline__ float dot2f(uint32_t a, uint32_t b, float acc) {
#if __has_builtin(__builtin_amdgcn_fdot2)
  return __builtin_amdgcn_fdot2(__builtin_bit_cast(half2v, a),
                                __builtin_bit_cast(half2v, b), acc, false);
#else
  half2v xx = __builtin_bit_cast(half2v, a);
  half2v yy = __builtin_bit_cast(half2v, b);
  return acc + (float)xx[0]*(float)yy[0] + (float)xx[1]*(float)yy[1];
#endif
}

__device__ __forceinline__ float dot2x4(uint4 w, uint4 h, float acc) {
  acc = dot2f(w.x, h.x, acc); acc = dot2f(w.y, h.y, acc);
  acc = dot2f(w.z, h.z, acc); acc = dot2f(w.w, h.w, acc);
  return acc;
}

__device__ __forceinline__ uint16_t f16b(float x) {
  _Float16 h = (_Float16)x;
  return __builtin_bit_cast(unsigned short, h);
}
__device__ __forceinline__ uint32_t pack2(float a, float b) {
  return (uint32_t)f16b(a) | ((uint32_t)f16b(b) << 16);
}
__device__ __forceinline__ float fast_tanh(float x) {
  float e = __expf(2.0f*x);
  return 1.0f - 2.0f/(e + 1.0f);
}
__device__ __forceinline__ float fast_silu(float zz) {
  return zz / (1.0f + __expf(-zz));
}

// quad_perm broadcast of lane K (0..3) within each quad — VALU pipe, no LDS.
template<int K>
__device__ __forceinline__ uint32_t qbcast(uint32_t v) {
  return (uint32_t)__builtin_amdgcn_mov_dpp((int)v, K*0x55, 0xf, 0xf, true);
}
template<int K>
__device__ __forceinline__ uint4 qbcast4(uint4 v) {
  uint4 r;
  r.x = qbcast<K>(v.x); r.y = qbcast<K>(v.y);
  r.z = qbcast<K>(v.z); r.w = qbcast<K>(v.w);
  return r;
}
// xor-1 / xor-2 neighbor fetch via DPP quad_perm (VALU, not DS pipe).
template<int CTRL>
__device__ __forceinline__ float dpp_xorf(float v) {
  int t = __builtin_amdgcn_mov_dpp(__builtin_bit_cast(int, v), CTRL, 0xf, 0xf, true);
  return __builtin_bit_cast(float, t);
}

// barrier that does NOT drain vmcnt (only LDS ordering needed between phases)
__device__ __forceinline__ void lds_barrier() {
  asm volatile("s_waitcnt lgkmcnt(0)" ::: "memory");
  __builtin_amdgcn_s_barrier();
  __builtin_amdgcn_sched_barrier(0);
}

// ---------------------------------------------------------------------------
// K0: pack weights to f16 pairs in ws (s folded into U), h0 -> h-slot 0.
// ws layout (uint32 words):
//   [0]      vhw  [128][512]  V_h f16 pairs (word = adjacent d-pair)
//   [65536]  uhw2 [1024][64]  U'_h INTERLEAVED column pairs:
//                             word k of row d = pack(U[d][k]*s[k], U[d][k+64]*s[k+64])
//   [131072] vxw  [128][512]
//   [196608] uxw  [1024][64]  (plain pair layout, used by inp_kernel)
// ---------------------------------------------------------------------------
__global__ void prep_kernel(const float* __restrict__ Uh, const float* __restrict__ Vh,
                            const float* __restrict__ sh, const float* __restrict__ Ux,
                            const float* __restrict__ Vx, const float* __restrict__ sx,
                            const float* __restrict__ h0, uint32_t* __restrict__ ws32,
                            float* __restrict__ hout) {
  int i = blockIdx.x*blockDim.x + threadIdx.x;
  int n = gridDim.x*blockDim.x;
  for (int p = i; p < 65536; p += n) {
    int r = p >> 9, dp = p & 511;
    ws32[p] = pack2(Vh[r*1024 + 2*dp], Vh[r*1024 + 2*dp + 1]);
  }
  for (int p = i; p < 65536; p += n) {
    int d = p >> 6, k = p & 63;
    ws32[65536 + p] = pack2(Uh[d*128 + k]      * sh[k],
                            Uh[d*128 + 64 + k] * sh[64 + k]);
  }
  for (int p = i; p < 65536; p += n) {
    int r = p >> 9, dp = p & 511;
    ws32[131072 + p] = pack2(Vx[r*1024 + 2*dp], Vx[r*1024 + 2*dp + 1]);
  }
  for (int p = i; p < 65536; p += n) {
    int d = p >> 6, rp = p & 63;
    ws32[196608 + p] = pack2(Ux[d*128 + 2*rp]   * sx[2*rp],
                             Ux[d*128 + 2*rp+1] * sx[2*rp+1]);
  }
  for (int p = i; p < BD; p += n) hout[p] = h0[p];
}

// ---------------------------------------------------------------------------
// K1: input branch. One WG per timestep t. (unchanged)
// ---------------------------------------------------------------------------
__global__ __launch_bounds__(512, 4) void inp_kernel(
    const float* __restrict__ x, const uint32_t* __restrict__ ws32,
    const float* __restrict__ bias, float* __restrict__ hout) {
  const int t = blockIdx.x;
  const int l = threadIdx.x;  // 0..511
  __shared__ __attribute__((aligned(16))) uint32_t xs[32*516];
  __shared__ __attribute__((aligned(16))) uint16_t svx[BATCH*RANK];

  const float4* xg = (const float4*)(x + (size_t)t*BD);
  #pragma unroll
  for (int k = 0; k < 16; k++) {
    int i = l + 512*k;
    float4 v = xg[i];
    int bb = i >> 8;
    int d4 = i & 255;
    xs[bb*516 + d4*2]     = pack2(v.x, v.y);
    xs[bb*516 + d4*2 + 1] = pack2(v.z, v.w);
  }
  __syncthreads();

  const int q4 = l & 3;
  const int r  = l >> 2;
  const uint4* wrow = (const uint4*)(ws32 + 131072 + r*512);
  float acc0[8], acc1[8];
  #pragma unroll
  for (int bi = 0; bi < 8; bi++) { acc0[bi] = 0.f; acc1[bi] = 0.f; }
  #pragma unroll 4
  for (int J = 0; J < 128; J += 2) {
    uint4 w0 = wrow[J];
    uint4 w1 = wrow[J+1];
    #pragma unroll
    for (int bi = 0; bi < 8; bi++) {
      const uint4* xrow = (const uint4*)(xs + (4*bi + q4)*516);
      uint4 h0v = xrow[J];
      acc0[bi] = dot2f(w0.x, h0v.x, acc0[bi]);
      acc0[bi] = dot2f(w0.y, h0v.y, acc0[bi]);
      acc0[bi] = dot2f(w0.z, h0v.z, acc0[bi]);
      acc0[bi] = dot2f(w0.w, h0v.w, acc0[bi]);
      uint4 h1v = xrow[J+1];
      acc1[bi] = dot2f(w1.x, h1v.x, acc1[bi]);
      acc1[bi] = dot2f(w1.y, h1v.y, acc1[bi]);
      acc1[bi] = dot2f(w1.z, h1v.z, acc1[bi]);
      acc1[bi] = dot2f(w1.w, h1v.w, acc1[bi]);
    }
  }
  #pragma unroll
  for (int bi = 0; bi < 8; bi++)
    svx[(4*bi + q4)*RANK + r] = f16b(acc0[bi] + acc1[bi]);
  __syncthreads();

  const uint4* svx4 = (const uint4*)svx;
  float accb[BATCH];
  #pragma unroll 1
  for (int dd = 0; dd < 2; dd++) {
    int d = l + dd*512;
    const uint4* urow = (const uint4*)(ws32 + 196608 + d*64);
    #pragma unroll
    for (int bi = 0; bi < BATCH; bi++) accb[bi] = 0.f;
    #pragma unroll
    for (int RP = 0; RP < 16; RP++) {
      uint4 w = urow[RP];
      #pragma unroll
      for (int bi = 0; bi < BATCH; bi++) {
        uint4 sv = svx4[bi*16 + RP];
        accb[bi] = dot2f(w.x, sv.x, accb[bi]);
        accb[bi] = dot2f(w.y, sv.y, accb[bi]);
        accb[bi] = dot2f(w.z, sv.z, accb[bi]);
        accb[bi] = dot2f(w.w, sv.w, accb[bi]);
      }
    }
    float bv = bias[d];
    float* cslot = hout + (size_t)(t+1)*BD + d;
    #pragma unroll
    for (int bi = 0; bi < BATCH; bi++)
      cslot[(size_t)bi*DIM] = accb[bi] + bv;
  }
}

// ---------------------------------------------------------------------------
// K2: recurrence v9. One WG (512 thr = 8 waves, 2 waves/SIMD) per batch b.
// KEY EXPERIMENT: no __launch_bounds__; instead the canonical LLVM pairing
//   amdgpu_flat_work_group_size(512,512) + amdgpu_waves_per_eu(2,2)
// (R6/R8 combined waves_per_eu WITH __launch_bounds__, which sets its own
// occupancy metadata and plausibly overrode the hint -> 128-reg bucket).
// If honored: 2 waves/EU x 256 VGPR = full register file, and weights are
// FULLY resident:
//   regs 416 KB: U rows 2l,2l+1 complete (128 words) + V rows 8R8+0..4 (80)
//   LDS   96 KB: V rows 8R8+5,6,7 (conflict-free interleave)
// Zero L2 weight streaming. DS/step = 20 b128/wave (12 V + 4 h + 4 svh)
// ~1900 cyc; VALU ~1400 cyc/SIMD; step ~2300 cyc.
// Readout: VGPR_Count >= 240 means the attribute stuck.
// ---------------------------------------------------------------------------
__global__ __attribute__((amdgpu_flat_work_group_size(512, 512),
                          amdgpu_waves_per_eu(2, 2)))
void rec_kernel(
    const uint32_t* __restrict__ ws32, const float* __restrict__ z,
    float* __restrict__ outb) {
  const int b  = blockIdx.x;
  const int l  = threadIdx.x;  // 0..511
  const int W  = l & 31;
  const int R8 = l >> 5;       // 0..15
  const int m  = l & 3;
  float* hout = outb + TBD;
  const uint4* vhw4 = (const uint4*)ws32;            // V: row stride 128 uint4
  const uint4* uhw4 = (const uint4*)(ws32 + 65536);  // U: row stride 16 uint4

  __shared__ __attribute__((aligned(16))) uint4    vlds[6144];   // 96 KB
  __shared__ __attribute__((aligned(16))) uint4    hbuf[32*5];   // 2.5 KB staggered
  __shared__ __attribute__((aligned(16))) uint32_t svh32[64];    // 256 B

  // V rows 8R8+0..4, window [16W,16W+16) pairs -> regs (80 VGPRs)
  uint4 vw[5][4];
  #pragma unroll
  for (int r = 0; r < 5; r++) {
    #pragma unroll
    for (int c = 0; c < 4; c++) vw[r][c] = vhw4[(8*R8 + r)*128 + W*4 + c];
  }
  // V rows 8R8+5,6,7 -> vlds (interleaved: idx = R8*384 + rr*128 + c*32 + W)
  #pragma unroll
  for (int rr = 0; rr < 3; rr++) {
    #pragma unroll
    for (int c = 0; c < 4; c++)
      vlds[R8*384 + rr*128 + c*32 + W] = vhw4[(8*R8 + 5 + rr)*128 + W*4 + c];
  }
  // U rows 2l,2l+1 COMPLETE (interleaved cols) -> regs (128 VGPRs)
  uint4 uqr0[16], uqr1[16];
  #pragma unroll
  for (int J = 0; J < 16; J++) { uqr0[J] = uhw4[(2*l)*16 + J]; uqr1[J] = uhw4[(2*l+1)*16 + J]; }
  // init hbuf from h0 (pair p=l at word 20*(p>>4) + (p&15))
  {
    const float2 v = ((const float2*)(hout + (size_t)b*DIM))[l];
    ((uint32_t*)hbuf)[20*(l>>4) + (l&15)] = pack2(v.x, v.y);
  }
  __syncthreads();

  const float2* zp2 = (const float2*)(z + (size_t)b*DIM) + l;
  float2*       cp2 = (float2*)(hout + BD + (size_t)b*DIM) + l;
  float2*       op2 = (float2*)(outb + (size_t)b*DIM) + l;
  const uint4*  hb4  = hbuf + W*5;
  const uint4*  svh4 = (const uint4*)svh32;
  const int vbase = R8*384;

  #pragma unroll 1
  for (int t = 0; t < T_STEPS; t++) {
    // ---- issue c (slot t+1) and z (slot t) loads: consumed in phase B ----
    float2 cc = *cp2;
    float2 zz = *zp2;

    // ---- phase A: 8 rows (5 reg + 3 LDS) x 16-pair window ----
    float a[8] = {0.f,0.f,0.f,0.f,0.f,0.f,0.f,0.f};
    #pragma unroll
    for (int c = 0; c < 4; c++) {
      uint4 hvc = hb4[c];
      uint4 vA = vlds[vbase + c*32 + W];
      uint4 vB = vlds[vbase + 128 + c*32 + W];
      uint4 vC = vlds[vbase + 256 + c*32 + W];
      a[0] = dot2x4(vw[0][c], hvc, a[0]);
      a[1] = dot2x4(vw[1][c], hvc, a[1]);
      a[2] = dot2x4(vw[2][c], hvc, a[2]);
      a[3] = dot2x4(vw[3][c], hvc, a[3]);
      a[4] = dot2x4(vw[4][c], hvc, a[4]);
      a[5] = dot2x4(vA, hvc, a[5]);
      a[6] = dot2x4(vB, hvc, a[6]);
      a[7] = dot2x4(vC, hvc, a[7]);
    }
    // reduce-scatter: row 8R8+(W&7) total lands in every lane of its group
    float b4[4];
    {
      const bool s0 = (W & 1);
      #pragma unroll
      for (int i = 0; i < 4; i++) {
        float keep = s0 ? a[2*i+1] : a[2*i];
        float send = s0 ? a[2*i]   : a[2*i+1];
        b4[i] = keep + dpp_xorf<0xB1>(send);   // quad_perm(1,0,3,2) = xor1
      }
    }
    float c2[2];
    {
      const bool s1 = (W >> 1) & 1;
      #pragma unroll
      for (int i = 0; i < 2; i++) {
        float keep = s1 ? b4[2*i+1] : b4[2*i];
        float send = s1 ? b4[2*i]   : b4[2*i+1];
        c2[i] = keep + dpp_xorf<0x4E>(send);   // quad_perm(2,3,0,1) = xor2
      }
    }
    float s;
    {
      const bool s2 = (W >> 2) & 1;
      float keep = s2 ? c2[1] : c2[0];
      float send = s2 ? c2[0] : c2[1];
      s = keep + __shfl_xor(send, 4);
    }
    s += __shfl_xor(s, 8);
    s += __shfl_xor(s, 16);
    if (W < 8) {
      int row = 8*R8 + W;                         // 0..127
      int idx = ((row & 63) << 1) | (row >> 6);   // packed (g, g+64) halves
      ((uint16_t*)svh32)[idx] = f16b(s);
    }
    lds_barrier();

    // ---- phase B: rows d=2l,2l+1; svh quad-read + DPP broadcast ----
    float p0 = 0.f, p1 = 0.f;
    { // quarter 0: k4 0..3
      uint4 svm = svh4[m];
      uint4 sv;
      sv = qbcast4<0>(svm); p0 = dot2x4(uqr0[0], sv, p0); p1 = dot2x4(uqr1[0], sv, p1);
      sv = qbcast4<1>(svm); p0 = dot2x4(uqr0[1], sv, p0); p1 = dot2x4(uqr1[1], sv, p1);
      sv = qbcast4<2>(svm); p0 = dot2x4(uqr0[2], sv, p0); p1 = dot2x4(uqr1[2], sv, p1);
      sv = qbcast4<3>(svm); p0 = dot2x4(uqr0[3], sv, p0); p1 = dot2x4(uqr1[3], sv, p1);
    }
    { // quarter 1: k4 4..7
      uint4 svm = svh4[4 + m];
      uint4 sv;
      sv = qbcast4<0>(svm); p0 = dot2x4(uqr0[4], sv, p0); p1 = dot2x4(uqr1[4], sv, p1);
      sv = qbcast4<1>(svm); p0 = dot2x4(uqr0[5], sv, p0); p1 = dot2x4(uqr1[5], sv, p1);
      sv = qbcast4<2>(svm); p0 = dot2x4(uqr0[6], sv, p0); p1 = dot2x4(uqr1[6], sv, p1);
      sv = qbcast4<3>(svm); p0 = dot2x4(uqr0[7], sv, p0); p1 = dot2x4(uqr1[7], sv, p1);
    }
    { // quarter 2: k4 8..11
      uint4 svm = svh4[8 + m];
      uint4 sv;
      sv = qbcast4<0>(svm); p0 = dot2x4(uqr0[8],  sv, p0); p1 = dot2x4(uqr1[8],  sv, p1);
      sv = qbcast4<1>(svm); p0 = dot2x4(uqr0[9],  sv, p0); p1 = dot2x4(uqr1[9],  sv, p1);
      sv = qbcast4<2>(svm); p0 = dot2x4(uqr0[10], sv, p0); p1 = dot2x4(uqr1[10], sv, p1);
      sv = qbcast4<3>(svm); p0 = dot2x4(uqr0[11], sv, p0); p1 = dot2x4(uqr1[11], sv, p1);
    }
    { // quarter 3: k4 12..15
      uint4 svm = svh4[12 + m];
      uint4 sv;
      sv = qbcast4<0>(svm); p0 = dot2x4(uqr0[12], sv, p0); p1 = dot2x4(uqr1[12], sv, p1);
      sv = qbcast4<1>(svm); p0 = dot2x4(uqr0[13], sv, p0); p1 = dot2x4(uqr1[13], sv, p1);
      sv = qbcast4<2>(svm); p0 = dot2x4(uqr0[14], sv, p0); p1 = dot2x4(uqr1[14], sv, p1);
      sv = qbcast4<3>(svm); p0 = dot2x4(uqr0[15], sv, p0); p1 = dot2x4(uqr1[15], sv, p1);
    }

    float hv0 = fast_tanh(p0 + cc.x);
    float hv1 = fast_tanh(p1 + cc.y);
    *cp2 = make_float2(hv0, hv1);                             // h[t+1] (f32 out)
    ((uint32_t*)hbuf)[20*(l>>4) + (l&15)] = pack2(hv0, hv1);  // h for next step
    *op2 = make_float2(hv0 * fast_silu(zz.x), hv1 * fast_silu(zz.y));
    lds_barrier();

    cp2 += BD/2; zp2 += BD/2; op2 += BD/2;
  }
}

extern "C" void kernel_launch(void* const* d_in, const int* in_sizes, int n_in,
                              void* d_out, int out_size, void* d_ws, size_t ws_size,
                              hipStream_t stream) {
  const float* x  = (const float*)d_in[0];
  const float* z  = (const float*)d_in[1];
  const float* h0 = (const float*)d_in[2];
  const float* Uh = (const float*)d_in[3];
  const float* Vh = (const float*)d_in[4];
  const float* sh = (const float*)d_in[5];
  const float* Ux = (const float*)d_in[6];
  const float* Vx = (const float*)d_in[7];
  const float* sx = (const float*)d_in[8];
  const float* bb = (const float*)d_in[9];
  float* outb = (float*)d_out;
  uint32_t* ws32 = (uint32_t*)d_ws;   // needs 1 MiB

  prep_kernel<<<512, 256, 0, stream>>>(Uh, Vh, sh, Ux, Vx, sx, h0, ws32, outb + TBD);
  inp_kernel<<<T_STEPS, 512, 0, stream>>>(x, ws32, bb, outb + TBD);
  rec_kernel<<<BATCH, 512, 0, stream>>>(ws32, z, outb);
}